// Round 3
// baseline (686.016 us; speedup 1.0000x reference)
//
#include <hip/hip_runtime.h>
#include <stdint.h>
#include <stddef.h>

#define IN_F 4096
#define OUT_F 4096
#define M_TOT 8192
// GEMM tile: 256x128 block, 4 waves of 128x64 each (8x4 frags of 16x16)
#define BM 256
#define BN 128
#define BK 64

typedef __attribute__((ext_vector_type(8))) short short8;     // 8 x bf16 MFMA A/B frag
typedef __attribute__((ext_vector_type(4))) float f32x4;      // MFMA C/D frag
typedef __attribute__((ext_vector_type(4))) float float4v;
typedef __attribute__((ext_vector_type(4))) unsigned short u16x4;
typedef __attribute__((ext_vector_type(8))) unsigned short u16x8;
typedef unsigned short u16;

// FP4 codebook (matches reference FP4_CODEBOOK exactly)
__constant__ float c_lut[16] = {
  0.0f, 0.0052f, 0.6667f, 1.0f, 0.3333f, 0.5f, 0.1667f, 0.25f,
  0.0f, -0.0052f, -0.6667f, -1.0f, -0.3333f, -0.5f, -0.1667f, -0.25f
};

// fp32 -> bf16 round-to-nearest-even
__device__ __forceinline__ u16 f2bf(float f) {
  unsigned int x = __float_as_uint(f);
  x += 0x7fffu + ((x >> 16) & 1u);
  return (u16)(x >> 16);
}

// async global->LDS, 16B per lane. LDS dest is wave-uniform base + lane*16.
__device__ __forceinline__ void gload_lds16(const u16* g, u16* lds) {
  __builtin_amdgcn_global_load_lds(
      (const __attribute__((address_space(1))) unsigned int*)g,
      (__attribute__((address_space(3))) unsigned int*)lds, 16, 0, 0);
}

// ---------- merged prep: W fp4 -> bf16 (blocks < 2048) + x fp32 -> bf16 ----------
__global__ __launch_bounds__(256) void k_prep(const int* __restrict__ wp,
                                              const float* __restrict__ scale,
                                              const float* __restrict__ x,
                                              u16* __restrict__ bW,
                                              u16* __restrict__ aX) {
  __shared__ float lut[16];
  if (threadIdx.x < 16) lut[threadIdx.x] = c_lut[threadIdx.x];
  __syncthreads();
  const int WBLK = 2048;
  if (blockIdx.x < WBLK) {
    const int ng = (OUT_F * IN_F / 2) / 4;  // int4 groups -> u16x8 out
    const int stride = WBLK * 256;
    for (int t = blockIdx.x * 256 + threadIdx.x; t < ng; t += stride) {
      int4 p = ((const int4*)wp)[t];
      float s = scale[t >> 3];
      int by[4] = {p.x, p.y, p.z, p.w};
      u16x8 o;
#pragma unroll
      for (int q = 0; q < 4; ++q) {
        o[2 * q]     = f2bf(lut[(by[q] >> 4) & 15] * s);
        o[2 * q + 1] = f2bf(lut[by[q] & 15] * s);
      }
      ((u16x8*)bW)[t] = o;
    }
  } else {
    const int n8 = (M_TOT * IN_F) / 8;
    const int stride = (gridDim.x - WBLK) * 256;
    for (int t = (blockIdx.x - WBLK) * 256 + threadIdx.x; t < n8; t += stride) {
      float4v f0 = ((const float4v*)x)[2 * t];
      float4v f1 = ((const float4v*)x)[2 * t + 1];
      u16x8 o;
      o[0] = f2bf(f0.x); o[1] = f2bf(f0.y); o[2] = f2bf(f0.z); o[3] = f2bf(f0.w);
      o[4] = f2bf(f1.x); o[5] = f2bf(f1.y); o[6] = f2bf(f1.z); o[7] = f2bf(f1.w);
      ((u16x8*)aX)[t] = o;
    }
  }
}

// ---------------- main GEMM: C = A(bf16, MxK) * B(bf16, NxK)^T + bias ----------------
// 256x128 block tile, 4 waves of 128x64 (8x4 frags of 16x16x32), BK=64.
// global_load_lds width=16 staging with XOR swizzle:
//   LDS chunk p (16B) of row r holds GLOBAL chunk p ^ (r&7);
//   staging reads global chunk (lane&7)^srow; frag reads chunk gc^(row&7).
__global__ __launch_bounds__(256) void k_gemm(const u16* __restrict__ A,
                                              const u16* __restrict__ B,
                                              const float* __restrict__ bias,
                                              float* __restrict__ C) {
  __shared__ u16 As[BM * BK];   // 32 KiB
  __shared__ u16 Bs[BN * BK];   // 16 KiB
  const int tid  = threadIdx.x;
  const int lane = tid & 63;
  const int wave = tid >> 6;
  const int mBase = blockIdx.y * BM;
  const int nBase = blockIdx.x * BN;
  const int wm = (wave >> 1) * 128;
  const int wn = (wave & 1) * 64;

  const int srow = lane >> 3;                          // 0..7
  const int scol = ((lane & 7) ^ srow) * 8;            // swizzled k offset (elements)

  const int frow = lane & 15;
  const int fx   = lane & 7;
  const int cq   = lane >> 4;

  f32x4 acc[8][4] = {};

  // wave-level staging base pointers (A: 64 rows/wave in 8 instrs; B: 32 rows/wave in 4)
  const u16* aG = A + (size_t)(mBase + wave * 64 + srow) * IN_F + scol;
  const u16* bG = B + (size_t)(nBase + wave * 32 + srow) * IN_F + scol;

  for (int kt = 0; kt < IN_F; kt += BK) {
#pragma unroll
    for (int q = 0; q < 8; ++q)
      gload_lds16(aG + (size_t)(q * 8) * IN_F + kt, &As[(wave * 64 + q * 8) * BK]);
#pragma unroll
    for (int q = 0; q < 4; ++q)
      gload_lds16(bG + (size_t)(q * 8) * IN_F + kt, &Bs[(wave * 32 + q * 8) * BK]);
    asm volatile("s_waitcnt vmcnt(0)" ::: "memory");
    __syncthreads();

#pragma unroll
    for (int ks = 0; ks < BK; ks += 32) {
      const int co = (((ks >> 3) + cq) ^ fx) << 3;   // swizzled element offset in row
      short8 b[4];
#pragma unroll
      for (int j = 0; j < 4; ++j)
        b[j] = *(const short8*)&Bs[(wn + j * 16 + frow) * BK + co];
#pragma unroll
      for (int h = 0; h < 2; ++h) {
        short8 a[4];
#pragma unroll
        for (int i = 0; i < 4; ++i)
          a[i] = *(const short8*)&As[(wm + (h * 4 + i) * 16 + frow) * BK + co];
#pragma unroll
        for (int i = 0; i < 4; ++i)
#pragma unroll
          for (int j = 0; j < 4; ++j)
            acc[h * 4 + i][j] =
                __builtin_amdgcn_mfma_f32_16x16x32_bf16(a[i], b[j], acc[h * 4 + i][j], 0, 0, 0);
      }
    }
    __syncthreads();
  }

  // epilogue: C/D layout col = lane&15, row = (lane>>4)*4 + reg   [m89-verified]
  const int ccol = lane & 15;
  const int crow = (lane >> 4) * 4;
#pragma unroll
  for (int j = 0; j < 4; ++j) {
    const int col = nBase + wn + j * 16 + ccol;
    const float bv = bias[col];
#pragma unroll
    for (int i = 0; i < 8; ++i) {
      const size_t rb = (size_t)(mBase + wm + i * 16 + crow) * OUT_F + col;
#pragma unroll
      for (int t = 0; t < 4; ++t)
        C[rb + (size_t)t * OUT_F] = acc[i][j][t] + bv;
    }
  }
}

// -------- fallback: fully fused (no workspace), 128x128 tile, own constants --------
#define FBM 128
#define FBN 128
__global__ __launch_bounds__(256) void k_gemm_fused(const float* __restrict__ X,
                                                    const int* __restrict__ WP,
                                                    const float* __restrict__ scale,
                                                    const float* __restrict__ bias,
                                                    float* __restrict__ C) {
  __shared__ u16 As[FBM * BK];
  __shared__ u16 Bs[FBN * BK];
  __shared__ float lut[16];
  const int tid = threadIdx.x;
  if (tid < 16) lut[tid] = c_lut[tid];
  const int lane = tid & 63;
  const int wave = tid >> 6;
  const int mBase = blockIdx.y * FBM;
  const int nBase = blockIdx.x * FBN;
  const int wm = (wave >> 1) * 64;
  const int wn = (wave & 1) * 64;
  const int frow = lane & 15;
  const int fx   = lane & 7;
  const int cq   = lane >> 4;
  f32x4 acc[4][4] = {};
  __syncthreads();  // lut ready

  for (int kt = 0; kt < IN_F; kt += BK) {
#pragma unroll
    for (int i = 0; i < 8; ++i) {
      const int g = tid + i * 256;
      const int r = g >> 4, c = (g & 15) * 4;
      float4v f = *(const float4v*)&X[(size_t)(mBase + r) * IN_F + kt + c];
      u16x4 o;
      o.x = f2bf(f.x); o.y = f2bf(f.y); o.z = f2bf(f.z); o.w = f2bf(f.w);
      *(u16x4*)&As[r * BK + ((((c >> 3) ^ (r & 7)) << 3) | (c & 7))] = o;
    }
#pragma unroll
    for (int i = 0; i < 4; ++i) {
      const int g = tid + i * 256;
      const int r = g >> 3, c4 = (g & 7) * 4;
      int4 p = *(const int4*)&WP[(size_t)(nBase + r) * (IN_F / 2) + (kt >> 1) + c4];
      const float s = scale[(nBase + r) * 64 + (kt >> 6)];
      int by[4] = {p.x, p.y, p.z, p.w};
      u16x8 o;
#pragma unroll
      for (int q = 0; q < 4; ++q) {
        o[2 * q]     = f2bf(lut[(by[q] >> 4) & 15] * s);
        o[2 * q + 1] = f2bf(lut[by[q] & 15] * s);
      }
      *(u16x8*)&Bs[r * BK + (((g & 7) ^ (r & 7)) << 3)] = o;
    }
    __syncthreads();
#pragma unroll
    for (int ks = 0; ks < BK; ks += 32) {
      const int co = (((ks >> 3) + cq) ^ fx) << 3;
      short8 a[4], b[4];
#pragma unroll
      for (int i = 0; i < 4; ++i)
        a[i] = *(const short8*)&As[(wm + i * 16 + frow) * BK + co];
#pragma unroll
      for (int j = 0; j < 4; ++j)
        b[j] = *(const short8*)&Bs[(wn + j * 16 + frow) * BK + co];
#pragma unroll
      for (int i = 0; i < 4; ++i)
#pragma unroll
        for (int j = 0; j < 4; ++j)
          acc[i][j] = __builtin_amdgcn_mfma_f32_16x16x32_bf16(a[i], b[j], acc[i][j], 0, 0, 0);
    }
    __syncthreads();
  }

  const int ccol = lane & 15;
  const int crow = (lane >> 4) * 4;
#pragma unroll
  for (int j = 0; j < 4; ++j) {
    const int col = nBase + wn + j * 16 + ccol;
    const float bv = bias[col];
#pragma unroll
    for (int i = 0; i < 4; ++i) {
      const size_t rb = (size_t)(mBase + wm + i * 16 + crow) * OUT_F + col;
#pragma unroll
      for (int t = 0; t < 4; ++t)
        C[rb + (size_t)t * OUT_F] = acc[i][j][t] + bv;
    }
  }
}

extern "C" void kernel_launch(void* const* d_in, const int* in_sizes, int n_in,
                              void* d_out, int out_size, void* d_ws, size_t ws_size,
                              hipStream_t stream) {
  const float* x  = (const float*)d_in[0];
  const int*   wp = (const int*)d_in[1];
  const float* sc = (const float*)d_in[2];
  const float* bi = (const float*)d_in[3];
  float* out = (float*)d_out;

  const size_t bBytes = (size_t)OUT_F * IN_F * 2;   // 33.5 MB bf16 W
  const size_t aBytes = (size_t)M_TOT * IN_F * 2;   // 67 MB bf16 x

  if (ws_size >= aBytes + bBytes) {
    u16* B = (u16*)d_ws;
    u16* A = (u16*)((char*)d_ws + bBytes);
    k_prep<<<6144, 256, 0, stream>>>(wp, sc, x, B, A);
    dim3 grid(OUT_F / BN, M_TOT / BM);              // (32, 32)
    k_gemm<<<grid, 256, 0, stream>>>(A, B, bi, out);
  } else {
    dim3 grid(OUT_F / FBN, M_TOT / FBM);            // (32, 64)
    k_gemm_fused<<<grid, 256, 0, stream>>>(x, wp, sc, bi, out);
  }
}